// Round 4
// baseline (664.700 us; speedup 1.0000x reference)
//
#include <hip/hip_runtime.h>

// ---------------------------------------------------------------------------
// KAN 2-layer forward, round 11.
// r7..r10 post-mortem: four sync/occupancy/MFMA-shape structures all land at
// 258-284us for L1 with identical counters. Absolute arithmetic: real MFMA
// pipe = 6.5% (derived MfmaUtil is gfx94x-formula, ~4x inflated), VALU ~20%,
// LDS ~25%, L2 ~30%, HBM 7%. Limiter = the per-step LDS round-trip convoy
// (DMA->LDS->barrier->ds_read), not any pipe.
// r11 deletes staging entirely:
//  - A-frags computed IN REGISTERS: mfma_32x32x16 A-layout is lane=row l&31,
//    k=hi*8+j  == exactly kan_act8(x[row][f]) for f = s*4 + kk*2 + hi.
//  - B-frags via coalesced global loads from TRANSPOSED W: WT[f][col] 16B
//    packs; lane-consecutive cols -> 2x512B segments per load. L2-resident.
//  - BM=128, 8 waves 4m x 2n, full-width BN, zero LDS, zero per-step
//    barriers; 256 blocks = 1/CU; 2 waves/SIMD. Act dup x2 (wn pair), B read
//    x4 (wm quad, L1-dedup'd; s_barrier every 8 steps bounds wave drift).
//  - 1/6 spline factor folded into prep_w.
// ---------------------------------------------------------------------------

typedef short s16x8 __attribute__((ext_vector_type(8)));  // 8 bf16 = 4 VGPRs
typedef float f32x4 __attribute__((ext_vector_type(4)));
typedef float f32x16 __attribute__((ext_vector_type(16)));

__device__ __forceinline__ unsigned pk2(float lo, float hi) {
  unsigned a = __float_as_uint(lo), b = __float_as_uint(hi);
  a = a + 0x7fffu + ((a >> 16) & 1u);
  b = b + 0x7fffu + ((b >> 16) & 1u);
  return __builtin_amdgcn_perm(b, a, 0x07060302u);  // {b.hi16, a.hi16}
}

__device__ __forceinline__ unsigned short f2bf(float f) {
  unsigned u = __float_as_uint(f);
  unsigned r = u + 0x7fffu + ((u >> 16) & 1u);
  return (unsigned short)(r >> 16);
}

// silu + 6 cubic B-spline bases (uniform extended grid, u = 1.5x+4.5, knots
// u=0..9; recursion ref-verified r1..r10). Packed bf16x8 [silu,b3'_0..5,0]
// where b3' = 6*b3 (the 1/6 is folded into the weights in prep_w).
__device__ __forceinline__ s16x8 kan_act8(float x) {
  float e = __expf(-x);
  float s = x * __builtin_amdgcn_rcpf(1.0f + e);
  float u = fmaf(x, 1.5f, 4.5f);
  float d[10];
#pragma unroll
  for (int j = 0; j < 10; ++j) d[j] = u - (float)j;
  float b1[8];
#pragma unroll
  for (int j = 0; j < 8; ++j) b1[j] = fmaxf(0.0f, 1.0f - fabsf(d[j + 1]));
  float B2[7];
#pragma unroll
  for (int j = 0; j < 7; ++j) B2[j] = d[j] * b1[j] - d[j + 3] * b1[j + 1];
  float b3[6];
#pragma unroll
  for (int j = 0; j < 6; ++j)
    b3[j] = d[j] * B2[j] - d[j + 4] * B2[j + 1];   // 6x the basis; W has /6
  union { uint4 u4; s16x8 v; } r;
  r.u4.x = pk2(s, b3[0]);
  r.u4.y = pk2(b3[1], b3[2]);
  r.u4.z = pk2(b3[3], b3[4]);
  r.u4.w = pk2(b3[5], 0.0f);
  return r.v;
}

// Transposed packed weights: WT[f][col] = s16x8 {base_w, spline_w*sc/6 x6, 0}.
// Chunk index = f*Ncols + col. Cols >= Nvalid zeroed (padding).
__global__ __launch_bounds__(256) void prep_w(
    const float* __restrict__ base_w, const float* __restrict__ spline_w,
    const float* __restrict__ scaler, short* __restrict__ WT,
    int F, int Ncols, int Nvalid) {
  int i = blockIdx.x * 256 + threadIdx.x;  // feature (coalesced reads)
  int n = blockIdx.y;                      // output col
  if (i >= F) return;
  s16x8 v;
#pragma unroll
  for (int k = 0; k < 8; ++k) v[k] = 0;
  if (n < Nvalid) {
    int idx = n * F + i;
    float sc = scaler[idx] * (1.0f / 6.0f);
    v[0] = (short)f2bf(base_w[idx]);
#pragma unroll
    for (int k = 0; k < 6; ++k) v[1 + k] = (short)f2bf(spline_w[idx * 6 + k] * sc);
  }
  *(s16x8*)&WT[((size_t)i * Ncols + n) * 8] = v;
}

// Register-only fused-activation GEMM. NT n-tiles/wave (BN = NT*64 full
// width). BM=128: 8 waves = 4m x 2n; wave (wm,wn) owns rows [wm*32,+32),
// cols [wn*NT*32,+NT*32). A-frag = kan_act8 in regs (lane=row r5, feature
// s*4+kk*2+hi). B-frag = global dwordx4 from WT (lane=col, coalesced).
// No LDS, no per-step barrier; s_barrier every 8 steps bounds wave drift
// so the wm-quad's shared B lines stay L1-resident.
template <int NT>
__global__ __launch_bounds__(512, 2) void kan_gemm(
    const float* __restrict__ X, const short* __restrict__ WT,
    float* __restrict__ Cp, int F, int span, long long pstride, int ldc) {
  constexpr int Ncols = NT * 64;
  const int t    = threadIdx.x;
  const int lane = t & 63;
  const int w    = t >> 6;
  const int wm   = w >> 1;
  const int wn   = w & 1;
  const int r5   = lane & 31;
  const int hi   = lane >> 5;
  const int m0   = blockIdx.x * 128 + wm * 32;
  const int c0   = wn * (NT * 32);
  const int f0   = blockIdx.z * span;

  // B chunk pointer: chunk index = (f)*Ncols + col; start f = f0 + hi.
  const s16x8* wpt = (const s16x8*)WT + (size_t)(f0 + hi) * Ncols + c0 + r5;
  // x: lane covers row m0+r5; features s*4 + {hi, 2+hi} both inside the
  // aligned float4 at (row, f0 + s*4).
  const f32x4* xq = (const f32x4*)(X + (size_t)(m0 + r5) * F + f0);

  f32x16 acc[NT] = {};
  const int nsteps = span >> 2;

  f32x4 xv = xq[0];  // features s*4 .. s*4+3 for step 0
  for (int ks = 0; ks < nsteps; ++ks) {
    // prefetch next step's x quad
    f32x4 xn;
    if (ks + 1 < nsteps) xn = xq[ks + 1];

    // kk = 0: B loads, act, MFMA
    s16x8 b0[NT];
#pragma unroll
    for (int nt = 0; nt < NT; ++nt) b0[nt] = wpt[nt * 32];
    s16x8 a0 = kan_act8(xv[hi]);          // feature s*4 + hi
#pragma unroll
    for (int nt = 0; nt < NT; ++nt)
      acc[nt] = __builtin_amdgcn_mfma_f32_32x32x16_bf16(a0, b0[nt], acc[nt], 0, 0, 0);

    // kk = 1
    s16x8 b1[NT];
#pragma unroll
    for (int nt = 0; nt < NT; ++nt) b1[nt] = wpt[2 * Ncols + nt * 32];
    s16x8 a1 = kan_act8(xv[2 + hi]);      // feature s*4 + 2 + hi
#pragma unroll
    for (int nt = 0; nt < NT; ++nt)
      acc[nt] = __builtin_amdgcn_mfma_f32_32x32x16_bf16(a1, b1[nt], acc[nt], 0, 0, 0);

    wpt += (size_t)4 * Ncols;
    xv = xn;
    // Convoy barrier: keep the 4 wm-waves (sharing B lines) within ~a step
    // so L1 dedups the 4x B re-read. No data deps -> bare barrier.
    if ((ks & 7) == 7) __builtin_amdgcn_s_barrier();
  }

  // C/D layout (32x32): col = lane&31, row = (reg&3)+8*(reg>>2)+4*hi
  // (verified r10). Lanes consecutive in col -> coalesced 128B segments.
  float* cpt = Cp + (size_t)blockIdx.z * (size_t)pstride;
#pragma unroll
  for (int nt = 0; nt < NT; ++nt) {
    int col = c0 + nt * 32 + r5;
#pragma unroll
    for (int reg = 0; reg < 16; ++reg) {
      int row = m0 + (reg & 3) + 8 * (reg >> 2) + 4 * hi;
      cpt[(size_t)row * ldc + col] = acc[nt][reg];
    }
  }
}

// h = LayerNorm(p0 + p1) over D=512, one wave per row.
__global__ __launch_bounds__(256) void ln_reduce(
    const float* __restrict__ p0, const float* __restrict__ p1,
    float* __restrict__ h, const float* __restrict__ gamma,
    const float* __restrict__ beta, int nparts) {
  int lane = threadIdx.x & 63;
  int wv   = threadIdx.x >> 6;
  int row  = blockIdx.x * 4 + wv;
  size_t base = (size_t)row * 512 + lane * 8;
  f32x4 v0 = *(const f32x4*)(p0 + base);
  f32x4 v1 = *(const f32x4*)(p0 + base + 4);
  if (nparts == 2) {
    f32x4 u0 = *(const f32x4*)(p1 + base);
    f32x4 u1 = *(const f32x4*)(p1 + base + 4);
#pragma unroll
    for (int k = 0; k < 4; ++k) { v0[k] += u0[k]; v1[k] += u1[k]; }
  }
  float s = 0.f, s2 = 0.f;
#pragma unroll
  for (int k = 0; k < 4; ++k) { s += v0[k] + v1[k]; s2 += v0[k]*v0[k] + v1[k]*v1[k]; }
#pragma unroll
  for (int m = 32; m >= 1; m >>= 1) {
    s  += __shfl_xor(s,  m, 64);
    s2 += __shfl_xor(s2, m, 64);
  }
  float mean = s * (1.0f / 512.0f);
  float var  = s2 * (1.0f / 512.0f) - mean * mean;
  float rstd = rsqrtf(var + 1e-5f);
  const f32x4 g0 = *(const f32x4*)(gamma + lane * 8);
  const f32x4 g1 = *(const f32x4*)(gamma + lane * 8 + 4);
  const f32x4 be0 = *(const f32x4*)(beta + lane * 8);
  const f32x4 be1 = *(const f32x4*)(beta + lane * 8 + 4);
#pragma unroll
  for (int k = 0; k < 4; ++k) {
    v0[k] = (v0[k] - mean) * rstd * g0[k] + be0[k];
    v1[k] = (v1[k] - mean) * rstd * g1[k] + be1[k];
  }
  *(f32x4*)(h + base) = v0;
  *(f32x4*)(h + base + 4) = v1;
}

// out[b][c<229] = p0[b][c] (+ p1[b][c]) from 256-wide padded partials.
__global__ __launch_bounds__(256) void out_reduce(
    const float* __restrict__ p0, const float* __restrict__ p1,
    float* __restrict__ out, int nparts) {
  int idx = blockIdx.x * 256 + threadIdx.x;
  int row = idx >> 8;
  int c   = idx & 255;
  float v = p0[idx];
  if (nparts == 2) v += p1[idx];
  if (c < 229) out[(size_t)row * 229 + c] = v;
}

extern "C" void kernel_launch(void* const* d_in, const int* in_sizes, int n_in,
                              void* d_out, int out_size, void* d_ws, size_t ws_size,
                              hipStream_t stream) {
  const float* x         = (const float*)d_in[0];
  const float* base_w1   = (const float*)d_in[1];
  const float* spline_w1 = (const float*)d_in[2];
  const float* scaler1   = (const float*)d_in[3];
  const float* ln_gamma  = (const float*)d_in[4];
  const float* ln_beta   = (const float*)d_in[5];
  const float* base_w2   = (const float*)d_in[6];
  const float* spline_w2 = (const float*)d_in[7];
  const float* scaler2   = (const float*)d_in[8];
  float* out = (float*)d_out;

  const int B = 16384, D_IN = 1280, D_HID = 512, D_OUT = 229;

  // ws layout: W1pT | W2pT | h | p0 | p1   (~113 MB with parts=2)
  const size_t szW1 = (size_t)D_IN * D_HID * 8 * 2;   // 10,485,760 (f-major)
  const size_t szW2 = (size_t)D_HID * 256 * 8 * 2;    //  2,097,152
  const size_t szH  = (size_t)B * D_HID * 4;          // 33,554,432
  const size_t szP  = (size_t)B * 512 * 4;            // 33,554,432 slot
  char* ws = (char*)d_ws;
  short* W1p = (short*)ws;
  short* W2p = (short*)(ws + szW1);
  float* h   = (float*)(ws + szW1 + szW2);
  float* p0  = (float*)(ws + szW1 + szW2 + szH);
  float* p1  = (float*)(ws + szW1 + szW2 + szH + szP);

  const int parts = (ws_size >= szW1 + szW2 + szH + 2 * szP) ? 2 : 1;
  const long long pstride = (long long)(szP / 4);  // elements = slot size

  prep_w<<<dim3(D_IN / 256, D_HID), 256, 0, stream>>>(
      base_w1, spline_w1, scaler1, W1p, D_IN, D_HID, D_HID);
  prep_w<<<dim3(D_HID / 256, 256), 256, 0, stream>>>(
      base_w2, spline_w2, scaler2, W2p, D_HID, 256, D_OUT);

  // layer 1: (16384 x 1280) -> split-K partials (16384 x 512) x parts
  // 128-row blocks, register-only: grid 128 x parts = 256 blocks.
  kan_gemm<8><<<dim3(B / 128, 1, parts), 512, 0, stream>>>(
      x, W1p, p0, D_IN, D_IN / parts, pstride, D_HID);

  ln_reduce<<<dim3(B / 4), 256, 0, stream>>>(p0, p1, h, ln_gamma, ln_beta, parts);

  // layer 2: (16384 x 512) -> split-K partials (16384 x 256) x parts
  kan_gemm<4><<<dim3(B / 128, 1, parts), 512, 0, stream>>>(
      h, W2p, p0, D_HID, D_HID / parts, pstride, 256);

  out_reduce<<<dim3(B * 256 / 256), 256, 0, stream>>>(p0, p1, out, parts);
}

// Round 5
// 444.248 us; speedup vs baseline: 1.4962x; 1.4962x over previous
//
#include <hip/hip_runtime.h>

// ---------------------------------------------------------------------------
// KAN 2-layer forward, round 12.
// Ledger: r7-r10 (B via LDS DMA + per-step barrier) all ~260us: LDS pipe
// ~60% busy incl 2e7 conflict-cycles = the dominant cost. r11 (all-register,
// no staging) 429us: B-load latency exposed bare (no prefetch, 2 waves/SIMD).
// r12 combines the proven halves:
//  - B: registers, direct from f-major WT (coalesced 2x512B per load),
//    double-buffered one SUPERSTEP ahead (bc/bn) -> latency hidden under
//    MFMA+act, no LDS traffic, no DMA convoy.
//  - A: staged via LDS in 8-feature SUPERSTEPS: all 512 threads act once
//    per superstep (no actor/idle split), ONE barrier per 8 features (half
//    of r10's), As 16KB, row stride 128B + chunk^=(row&7) swizzle = uniform
//    banks. x scalar loads 2 supersteps ahead.
//  - mfma_32x32x16, BM=64, 8 waves n-major (wave = NT*32 cols), acc 64 AGPR,
//    ~90 VGPR -> no spill; 1 block/CU accepted (pipelining, not waves,
//    hides latency -- r9 proved waves alone don't).
// ---------------------------------------------------------------------------

typedef short s16x8 __attribute__((ext_vector_type(8)));  // 8 bf16 = 4 VGPRs
typedef float f32x4 __attribute__((ext_vector_type(4)));
typedef float f32x16 __attribute__((ext_vector_type(16)));

__device__ __forceinline__ unsigned pk2(float lo, float hi) {
  unsigned a = __float_as_uint(lo), b = __float_as_uint(hi);
  a = a + 0x7fffu + ((a >> 16) & 1u);
  b = b + 0x7fffu + ((b >> 16) & 1u);
  return __builtin_amdgcn_perm(b, a, 0x07060302u);  // {b.hi16, a.hi16}
}

__device__ __forceinline__ unsigned short f2bf(float f) {
  unsigned u = __float_as_uint(f);
  unsigned r = u + 0x7fffu + ((u >> 16) & 1u);
  return (unsigned short)(r >> 16);
}

// silu + 6 cubic B-spline bases (uniform extended grid, u = 1.5x+4.5, knots
// u=0..9; recursion ref-verified r1..r11). Packed bf16x8 [silu,b3'_0..5,0]
// where b3' = 6*b3 (the 1/6 is folded into the weights in prep_w).
__device__ __forceinline__ s16x8 kan_act8(float x) {
  float e = __expf(-x);
  float s = x * __builtin_amdgcn_rcpf(1.0f + e);
  float u = fmaf(x, 1.5f, 4.5f);
  float d[10];
#pragma unroll
  for (int j = 0; j < 10; ++j) d[j] = u - (float)j;
  float b1[8];
#pragma unroll
  for (int j = 0; j < 8; ++j) b1[j] = fmaxf(0.0f, 1.0f - fabsf(d[j + 1]));
  float B2[7];
#pragma unroll
  for (int j = 0; j < 7; ++j) B2[j] = d[j] * b1[j] - d[j + 3] * b1[j + 1];
  float b3[6];
#pragma unroll
  for (int j = 0; j < 6; ++j)
    b3[j] = d[j] * B2[j] - d[j + 4] * B2[j + 1];   // 6x the basis; W has /6
  union { uint4 u4; s16x8 v; } r;
  r.u4.x = pk2(s, b3[0]);
  r.u4.y = pk2(b3[1], b3[2]);
  r.u4.z = pk2(b3[3], b3[4]);
  r.u4.w = pk2(b3[5], 0.0f);
  return r.v;
}

// Transposed packed weights: WT[f][col] = s16x8 {base_w, spline_w*sc/6 x6, 0}.
// Chunk index = f*Ncols + col. Cols >= Nvalid zeroed (padding).
__global__ __launch_bounds__(256) void prep_w(
    const float* __restrict__ base_w, const float* __restrict__ spline_w,
    const float* __restrict__ scaler, short* __restrict__ WT,
    int F, int Ncols, int Nvalid) {
  int i = blockIdx.x * 256 + threadIdx.x;  // feature (coalesced reads)
  int n = blockIdx.y;                      // output col
  if (i >= F) return;
  s16x8 v;
#pragma unroll
  for (int k = 0; k < 8; ++k) v[k] = 0;
  if (n < Nvalid) {
    int idx = n * F + i;
    float sc = scaler[idx] * (1.0f / 6.0f);
    v[0] = (short)f2bf(base_w[idx]);
#pragma unroll
    for (int k = 0; k < 6; ++k) v[1 + k] = (short)f2bf(spline_w[idx * 6 + k] * sc);
  }
  *(s16x8*)&WT[((size_t)i * Ncols + n) * 8] = v;
}

// Superstep fused-act GEMM. BM=64, Ncols = NT*256 (8 waves x NT*32 cols),
// superstep = 8 features = 4 mfma-k-slots (kq). A: LDS dbuf, 64 rows x 8
// chunks of 16B, row stride 128B, chunk ^= row&7 (uniform banks); all 512
// threads act once/superstep. B: registers from WT, next superstep
// prefetched into bn. One barrier per superstep (orders the As ds_write).
template <int NT>
__global__ __launch_bounds__(512, 2) void kan_gemm(
    const float* __restrict__ X, const short* __restrict__ WT,
    float* __restrict__ Cp, int F, int span, long long pstride, int ldc) {
  constexpr int Ncols = NT * 256;
  __shared__ __align__(16) short As[2][64 * 64];  // 2 x 8KB

  const int t  = threadIdx.x;
  const int lane = t & 63;
  const int w  = t >> 6;
  const int r5 = lane & 31;
  const int hi = lane >> 5;
  const int m0 = blockIdx.x * 64;
  const int f0 = blockIdx.z * span;
  const int c0 = w * (NT * 32);
  const int s3 = r5 & 7;           // A chunk-swizzle key (row&7)
  const int a_lo = r5 * 64;        // shorts; +2048 for mt=1 (rows 32..63)

  // act staging: thread -> (row sr, feature sj in 0..7)
  const int sr = t >> 3, sj = t & 7;
  const float* xq = X + (size_t)(m0 + sr) * F + f0 + sj;
  const int aw = sr * 64 + ((sj ^ (sr & 7)) * 8);

  // B: lane -> col c0 + nt*32 + r5, feature kq*2 + hi (+8 per superstep)
  const s16x8* wpt = (const s16x8*)WT + (size_t)(f0 + hi) * Ncols + c0 + r5;

  f32x16 acc[2][NT] = {};
  const int nss = span >> 3;  // supersteps

  // prologue: B for ss=0; act+stage ss=0; x for ss=1, ss=2
  s16x8 bc[4][NT], bn[4][NT];
#pragma unroll
  for (int kq = 0; kq < 4; ++kq)
#pragma unroll
    for (int nt = 0; nt < NT; ++nt)
      bc[kq][nt] = wpt[(size_t)(kq * 2) * Ncols + nt * 32];
  {
    s16x8 a = kan_act8(xq[0]);
    *(s16x8*)&As[0][aw] = a;
  }
  float xn1 = xq[8];
  float xn2 = xq[16 < span ? 16 : 8];
  __syncthreads();

  for (int ss = 0; ss < nss; ++ss) {
    const int cb = ss & 1, nb = cb ^ 1;
    const bool more = (ss + 1 < nss);

    // x for superstep ss+3 (2-superstep use distance, clamped)
    int pf = ss + 3 < nss ? ss + 3 : nss - 1;
    float xn0 = xq[(size_t)pf * 8];

    // B prefetch for ss+1 (full superstep of latency cover)
    if (more) {
      const s16x8* wn = wpt + (size_t)(ss + 1) * 8 * Ncols;
#pragma unroll
      for (int kq = 0; kq < 4; ++kq)
#pragma unroll
        for (int nt = 0; nt < NT; ++nt)
          bn[kq][nt] = wn[(size_t)(kq * 2) * Ncols + nt * 32];
    }

    // MFMA over the 4 k-slots of this superstep
    const short* Ac = As[cb];
#pragma unroll
    for (int kq = 0; kq < 4; ++kq) {
      const int co = ((kq * 2 + hi) ^ s3) * 8;
      s16x8 a0 = *(const s16x8*)(Ac + a_lo + co);
      s16x8 a1 = *(const s16x8*)(Ac + a_lo + 2048 + co);
#pragma unroll
      for (int nt = 0; nt < NT; ++nt) {
        acc[0][nt] = __builtin_amdgcn_mfma_f32_32x32x16_bf16(
            a0, bc[kq][nt], acc[0][nt], 0, 0, 0);
        acc[1][nt] = __builtin_amdgcn_mfma_f32_32x32x16_bf16(
            a1, bc[kq][nt], acc[1][nt], 0, 0, 0);
      }
    }

    // stage next superstep's acts
    if (more) {
      s16x8 a = kan_act8(xn1);
      *(s16x8*)&As[nb][aw] = a;
      xn1 = xn2; xn2 = xn0;
    }
    asm volatile("s_waitcnt lgkmcnt(0)" ::: "memory");
    __builtin_amdgcn_s_barrier();
#pragma unroll
    for (int kq = 0; kq < 4; ++kq)
#pragma unroll
      for (int nt = 0; nt < NT; ++nt)
        bc[kq][nt] = bn[kq][nt];
  }

  // C/D layout (32x32): col = lane&31, row = (reg&3)+8*(reg>>2)+4*hi
  // (verified r10/r11). Lanes consecutive in col -> coalesced segments.
  float* cpt = Cp + (size_t)blockIdx.z * (size_t)pstride;
#pragma unroll
  for (int mt = 0; mt < 2; ++mt) {
#pragma unroll
    for (int nt = 0; nt < NT; ++nt) {
      int col = c0 + nt * 32 + r5;
#pragma unroll
      for (int reg = 0; reg < 16; ++reg) {
        int row = m0 + mt * 32 + (reg & 3) + 8 * (reg >> 2) + 4 * hi;
        cpt[(size_t)row * ldc + col] = acc[mt][nt][reg];
      }
    }
  }
}

// h = LayerNorm(p0 + p1) over D=512, one wave per row.
__global__ __launch_bounds__(256) void ln_reduce(
    const float* __restrict__ p0, const float* __restrict__ p1,
    float* __restrict__ h, const float* __restrict__ gamma,
    const float* __restrict__ beta, int nparts) {
  int lane = threadIdx.x & 63;
  int wv   = threadIdx.x >> 6;
  int row  = blockIdx.x * 4 + wv;
  size_t base = (size_t)row * 512 + lane * 8;
  f32x4 v0 = *(const f32x4*)(p0 + base);
  f32x4 v1 = *(const f32x4*)(p0 + base + 4);
  if (nparts == 2) {
    f32x4 u0 = *(const f32x4*)(p1 + base);
    f32x4 u1 = *(const f32x4*)(p1 + base + 4);
#pragma unroll
    for (int k = 0; k < 4; ++k) { v0[k] += u0[k]; v1[k] += u1[k]; }
  }
  float s = 0.f, s2 = 0.f;
#pragma unroll
  for (int k = 0; k < 4; ++k) { s += v0[k] + v1[k]; s2 += v0[k]*v0[k] + v1[k]*v1[k]; }
#pragma unroll
  for (int m = 32; m >= 1; m >>= 1) {
    s  += __shfl_xor(s,  m, 64);
    s2 += __shfl_xor(s2, m, 64);
  }
  float mean = s * (1.0f / 512.0f);
  float var  = s2 * (1.0f / 512.0f) - mean * mean;
  float rstd = rsqrtf(var + 1e-5f);
  const f32x4 g0 = *(const f32x4*)(gamma + lane * 8);
  const f32x4 g1 = *(const f32x4*)(gamma + lane * 8 + 4);
  const f32x4 be0 = *(const f32x4*)(beta + lane * 8);
  const f32x4 be1 = *(const f32x4*)(beta + lane * 8 + 4);
#pragma unroll
  for (int k = 0; k < 4; ++k) {
    v0[k] = (v0[k] - mean) * rstd * g0[k] + be0[k];
    v1[k] = (v1[k] - mean) * rstd * g1[k] + be1[k];
  }
  *(f32x4*)(h + base) = v0;
  *(f32x4*)(h + base + 4) = v1;
}

// out[b][c<229] = p0[b][c] (+ p1[b][c]) from 256-wide padded partials.
__global__ __launch_bounds__(256) void out_reduce(
    const float* __restrict__ p0, const float* __restrict__ p1,
    float* __restrict__ out, int nparts) {
  int idx = blockIdx.x * 256 + threadIdx.x;
  int row = idx >> 8;
  int c   = idx & 255;
  float v = p0[idx];
  if (nparts == 2) v += p1[idx];
  if (c < 229) out[(size_t)row * 229 + c] = v;
}

extern "C" void kernel_launch(void* const* d_in, const int* in_sizes, int n_in,
                              void* d_out, int out_size, void* d_ws, size_t ws_size,
                              hipStream_t stream) {
  const float* x         = (const float*)d_in[0];
  const float* base_w1   = (const float*)d_in[1];
  const float* spline_w1 = (const float*)d_in[2];
  const float* scaler1   = (const float*)d_in[3];
  const float* ln_gamma  = (const float*)d_in[4];
  const float* ln_beta   = (const float*)d_in[5];
  const float* base_w2   = (const float*)d_in[6];
  const float* spline_w2 = (const float*)d_in[7];
  const float* scaler2   = (const float*)d_in[8];
  float* out = (float*)d_out;

  const int B = 16384, D_IN = 1280, D_HID = 512, D_OUT = 229;

  // ws layout: W1pT | W2pT | h | p0 | p1   (~113 MB with parts=2)
  const size_t szW1 = (size_t)D_IN * D_HID * 8 * 2;   // 10,485,760 (f-major)
  const size_t szW2 = (size_t)D_HID * 256 * 8 * 2;    //  2,097,152
  const size_t szH  = (size_t)B * D_HID * 4;          // 33,554,432
  const size_t szP  = (size_t)B * 512 * 4;            // 33,554,432 slot
  char* ws = (char*)d_ws;
  short* W1p = (short*)ws;
  short* W2p = (short*)(ws + szW1);
  float* h   = (float*)(ws + szW1 + szW2);
  float* p0  = (float*)(ws + szW1 + szW2 + szH);
  float* p1  = (float*)(ws + szW1 + szW2 + szH + szP);

  const int parts = (ws_size >= szW1 + szW2 + szH + 2 * szP) ? 2 : 1;
  const long long pstride = (long long)(szP / 4);  // elements = slot size

  prep_w<<<dim3(D_IN / 256, D_HID), 256, 0, stream>>>(
      base_w1, spline_w1, scaler1, W1p, D_IN, D_HID, D_HID);
  prep_w<<<dim3(D_HID / 256, 256), 256, 0, stream>>>(
      base_w2, spline_w2, scaler2, W2p, D_HID, 256, D_OUT);

  // layer 1: (16384 x 1280) -> split-K partials (16384 x 512) x parts
  kan_gemm<2><<<dim3(B / 64, 1, parts), 512, 0, stream>>>(
      x, W1p, p0, D_IN, D_IN / parts, pstride, D_HID);

  ln_reduce<<<dim3(B / 4), 256, 0, stream>>>(p0, p1, h, ln_gamma, ln_beta, parts);

  // layer 2: (16384 x 512) -> split-K partials (16384 x 256) x parts
  kan_gemm<1><<<dim3(B / 64, 1, parts), 512, 0, stream>>>(
      h, W2p, p0, D_HID, D_HID / parts, pstride, 256);

  out_reduce<<<dim3(B * 256 / 256), 256, 0, stream>>>(p0, p1, out, parts);
}